// Round 1
// 298.786 us; speedup vs baseline: 1.0403x; 1.0403x over previous
//
#include <hip/hip_runtime.h>

// out[k] = exp(-r * (nc[i_k] - nc[j_k] + values[k]))
// indices are int32 pairs (i,j) interleaved.
//
// R5: FULL-coverage 12-bit fixed-point LDS table (100% of 100000 nodes).
// R4 (fp16, 81920 entries = 82%) left 18% of the 40M gathers on a divergent
// global fallback: with 64 lanes/wave, nearly every wave executed BOTH paths
// of all 8 conditional gathers per iteration (exec-mask juggling + 7.2M
// scattered 64B L2 line-pulls + vmcnt serialization at 4 waves/SIMD).
// Ladder: R1 pure-L2 226us -> R3 41% LDS 170us -> R4 82% LDS <95us.
// This closes coverage to 100%: no compares, no branches, no global gathers.
//
// Encoding: q = rint(nc * 2047/maxabs) + 2048 (12 bits), 8 entries packed in
// 3 dwords -> 150000 B for 100000 nodes, fits 160 KiB LDS. maxabs is computed
// by a per-block reduction (no clamp risk, scale adapts to the data). Step =
// maxabs/2047 ~ 0.0023 -> per-entry err 0.0012, BETTER than the fp16 table at
// the |nc|~4.8 tail (fp16 ulp 0.0039). The +2048 offsets cancel in the i-j
// difference, so dequant is one cvt + the existing fma:
//   out = expf( (qi-qj) * (r*step) + r*v ).

#define N_NODES   100000                    // fixed by the problem
#define TABLE_B   ((N_NODES * 3 + 1) / 2)   // 150000 bytes (16B-aligned)
#define LDS_BYTES (TABLE_B + 128)           // + reduction scratch

typedef float v4f __attribute__((ext_vector_type(4)));
typedef int   v4i __attribute__((ext_vector_type(4)));

__device__ __forceinline__ int q12(const unsigned char* __restrict__ tab,
                                   unsigned e) {
    unsigned o  = (e * 3u) >> 1;        // byte offset of the 12-bit field
    unsigned sh = (e & 1u) << 2;        // nibble shift for odd entries
    unsigned b  = (unsigned)tab[o] | ((unsigned)tab[o + 1] << 8);
    return (int)((b >> sh) & 0xFFFu);
}

__global__ __launch_bounds__(1024) void logit_kernel(
    const float* __restrict__ values,
    const float* __restrict__ nc,
    const float* __restrict__ rat,
    const int*   __restrict__ idx,
    float*       __restrict__ out,
    int n4)   // number of float4 groups (NNZ/4)
{
    extern __shared__ unsigned char smem[];
    unsigned char* tab   = smem;
    unsigned int*  tab32 = (unsigned int*)smem;
    float*         red   = (float*)(smem + TABLE_B);

    const int tid = threadIdx.x;
    const v4f* nc4 = (const v4f*)nc;

    // ---- pass 1: block-wide max|nc| (reads are L2/L3-resident, 400KB) ----
    float m = 0.0f;
    for (int k = tid; k < (N_NODES >> 2); k += blockDim.x) {
        v4f a = nc4[k];
        m = fmaxf(m, fmaxf(fmaxf(__builtin_fabsf(a.x), __builtin_fabsf(a.y)),
                           fmaxf(__builtin_fabsf(a.z), __builtin_fabsf(a.w))));
    }
    #pragma unroll
    for (int off = 32; off; off >>= 1)
        m = fmaxf(m, __shfl_xor(m, off));
    if ((tid & 63) == 0) red[tid >> 6] = m;
    __syncthreads();
    if (tid == 0) {
        float s = red[0];
        for (int w = 1; w < (int)(blockDim.x >> 6); ++w) s = fmaxf(s, red[w]);
        red[0] = s;
    }
    __syncthreads();
    const float maxabs = red[0];
    const float S      = 2047.0f / maxabs;
    const float step   = maxabs * (1.0f / 2047.0f);

    // ---- pass 2: quantize + pack 8 entries -> 3 dwords (L2-warm reads) ----
    for (int g = tid; g < (N_NODES >> 3); g += blockDim.x) {
        v4f a = nc4[2 * g];
        v4f b = nc4[2 * g + 1];
        int q0 = (int)rintf(a.x * S) + 2048;
        int q1 = (int)rintf(a.y * S) + 2048;
        int q2 = (int)rintf(a.z * S) + 2048;
        int q3 = (int)rintf(a.w * S) + 2048;
        int q4 = (int)rintf(b.x * S) + 2048;
        int q5 = (int)rintf(b.y * S) + 2048;
        int q6 = (int)rintf(b.z * S) + 2048;
        int q7 = (int)rintf(b.w * S) + 2048;
        tab32[3 * g + 0] = (unsigned)q0 | ((unsigned)q1 << 12) |
                           ((unsigned)(q2 & 0xFF) << 24);
        tab32[3 * g + 1] = (unsigned)(q2 >> 8) | ((unsigned)q3 << 4) |
                           ((unsigned)q4 << 16) | ((unsigned)(q5 & 0xF) << 28);
        tab32[3 * g + 2] = (unsigned)(q5 >> 4) | ((unsigned)q6 << 8) |
                           ((unsigned)q7 << 20);
    }
    __syncthreads();

    // ---- main streaming loop: 16B/elem HBM, all gathers from LDS ----
    const float r = -rat[0];
    const float c = r * step;           // folds dequant into the fma

    const v4f* v4 = (const v4f*)values;
    const v4i* i4 = (const v4i*)idx;
    v4f*       o4 = (v4f*)out;

    const int stride = gridDim.x * blockDim.x;
    for (int t = blockIdx.x * blockDim.x + tid; t < n4; t += stride) {
        v4f v  = __builtin_nontemporal_load(&v4[t]);
        v4i ab = __builtin_nontemporal_load(&i4[2 * t]);
        v4i cd = __builtin_nontemporal_load(&i4[2 * t + 1]);

        int d0 = q12(tab, (unsigned)ab.x) - q12(tab, (unsigned)ab.y);
        int d1 = q12(tab, (unsigned)ab.z) - q12(tab, (unsigned)ab.w);
        int d2 = q12(tab, (unsigned)cd.x) - q12(tab, (unsigned)cd.y);
        int d3 = q12(tab, (unsigned)cd.z) - q12(tab, (unsigned)cd.w);

        v4f o;
        o.x = __expf(fmaf((float)d0, c, r * v.x));
        o.y = __expf(fmaf((float)d1, c, r * v.y));
        o.z = __expf(fmaf((float)d2, c, r * v.z));
        o.w = __expf(fmaf((float)d3, c, r * v.w));

        __builtin_nontemporal_store(o, &o4[t]);
    }
}

extern "C" void kernel_launch(void* const* d_in, const int* in_sizes, int n_in,
                              void* d_out, int out_size, void* d_ws, size_t ws_size,
                              hipStream_t stream) {
    const float* values = (const float*)d_in[0];
    const float* nc     = (const float*)d_in[1];
    const float* rat    = (const float*)d_in[2];
    const int*   idx    = (const int*)d_in[3];
    float*       out    = (float*)d_out;

    int nnz = in_sizes[0];   // 20,000,000 — divisible by 4
    int n4  = nnz / 4;

    (void)hipFuncSetAttribute((const void*)logit_kernel,
                              hipFuncAttributeMaxDynamicSharedMemorySize,
                              (int)LDS_BYTES);

    // 256 blocks (1 block/CU at ~150KiB LDS), grid-stride over n4.
    logit_kernel<<<256, 1024, LDS_BYTES, stream>>>(values, nc, rat, idx, out, n4);
}